// Round 2
// baseline (178.832 us; speedup 1.0000x reference)
//
#include <hip/hip_runtime.h>
#include <stdint.h>

#define N_BATCH 32
#define B_OBJ   36
#define D_DIM   2048
#define Q_DIM   1024

typedef __bf16 bf16x8 __attribute__((ext_vector_type(8)));
typedef float  f32x4  __attribute__((ext_vector_type(4)));

__device__ __forceinline__ uint16_t f2bf(float f) {
    uint32_t u = __builtin_bit_cast(uint32_t, f);
    uint32_t r = (u + 0x7FFFu + ((u >> 16) & 1u)) >> 16;   // RNE
    return (uint16_t)r;
}

__device__ __forceinline__ void gld_lds16(const void* g, void* l) {
    __builtin_amdgcn_global_load_lds(
        (const __attribute__((address_space(1))) uint32_t*)g,
        (__attribute__((address_space(3))) uint32_t*)l, 16, 0, 0);
}

// ---- transpose + fp32->bf16, 64x64 tiles, vectorized ----
__global__ __launch_bounds__(256) void transpose_all(
    const float* __restrict__ W1, const float* __restrict__ W2,
    const float* __restrict__ W3,
    uint16_t* __restrict__ W1t, uint16_t* __restrict__ W2t,
    uint16_t* __restrict__ W3t) {
    __shared__ float tile[64][65];
    int gy = blockIdx.y;
    const float* W; uint16_t* Wt; int K, k0;
    if (gy < 32)      { W = W1; Wt = W1t; K = 2048; k0 = gy * 64; }
    else if (gy < 64) { W = W2; Wt = W2t; K = 2048; k0 = (gy - 32) * 64; }
    else              { W = W3; Wt = W3t; K = 1024; k0 = (gy - 64) * 64; }
    int n0 = blockIdx.x * 64;
    int t = threadIdx.x;
    {
        int r = t >> 4, c = (t & 15) * 4;
#pragma unroll
        for (int p = 0; p < 4; ++p)
            *(float4*)&tile[r + p * 16][c] =
                *(const float4*)&W[(size_t)(k0 + r + p * 16) * 2048 + n0 + c];
    }
    __syncthreads();
    {
        int n = t >> 2, kb = (t & 3) * 16;
#pragma unroll
        for (int g4 = 0; g4 < 4; ++g4) {
            int k = kb + g4 * 4;
            ushort4 o;
            o.x = f2bf(tile[k][n]);     o.y = f2bf(tile[k + 1][n]);
            o.z = f2bf(tile[k + 2][n]); o.w = f2bf(tile[k + 3][n]);
            *(ushort4*)&Wt[(size_t)(n0 + n) * K + k0 + k] = o;
        }
    }
}

// ---- qe GEMM: qpart[z] = q @ W3 over K-chunk z (M=32, N=2048, split-K=4) ----
__global__ __launch_bounds__(256) void qk_gemm(
    const float* __restrict__ q,
    const uint16_t* __restrict__ W3t,
    float* __restrict__ qpart) {
    __shared__ __align__(16) uint16_t As[32][32];
    __shared__ __align__(16) uint16_t Bs[128][32];
    int t = threadIdx.x, lane = t & 63, wave = t >> 6;
    int l15 = lane & 15, quad = lane >> 4;
    int n0 = blockIdx.x * 128;
    int kbase = blockIdx.y * 256;
    f32x4 acc[2][2] = {};
    int ar = t >> 3, ac = (t & 7) * 4;
    int br = t >> 2, bk = (t & 3) * 8;

    for (int k0 = 0; k0 < 256; k0 += 32) {
        __syncthreads();
        float4 av = *(const float4*)&q[(size_t)ar * Q_DIM + kbase + k0 + ac];
        ushort4 a4;
        a4.x = f2bf(av.x); a4.y = f2bf(av.y); a4.z = f2bf(av.z); a4.w = f2bf(av.w);
        *(ushort4*)&As[ar][ac] = a4;
        *(uint4*)&Bs[br][bk]      = *(const uint4*)&W3t[(size_t)(n0 + br) * Q_DIM + kbase + k0 + bk];
        *(uint4*)&Bs[br + 64][bk] = *(const uint4*)&W3t[(size_t)(n0 + br + 64) * Q_DIM + kbase + k0 + bk];
        __syncthreads();
        bf16x8 af[2], bfr[2];
        af[0]  = *(const bf16x8*)&As[l15][quad * 8];
        af[1]  = *(const bf16x8*)&As[16 + l15][quad * 8];
        bfr[0] = *(const bf16x8*)&Bs[wave * 32 + l15][quad * 8];
        bfr[1] = *(const bf16x8*)&Bs[wave * 32 + 16 + l15][quad * 8];
#pragma unroll
        for (int i = 0; i < 2; ++i)
#pragma unroll
            for (int j = 0; j < 2; ++j)
                acc[i][j] = __builtin_amdgcn_mfma_f32_16x16x32_bf16(af[i], bfr[j], acc[i][j], 0, 0, 0);
    }
    float* dst = qpart + (size_t)blockIdx.y * 32 * D_DIM;
#pragma unroll
    for (int i = 0; i < 2; ++i)
#pragma unroll
        for (int j = 0; j < 2; ++j) {
            int n = n0 + wave * 32 + j * 16 + l15;
#pragma unroll
            for (int r = 0; r < 4; ++r)
                dst[(size_t)(i * 16 + quad * 4 + r) * D_DIM + n] = acc[i][j][r];
        }
}

// ---- qe = relu(sum_z qpart + b3) ----
__global__ void qe_reduce(const float* __restrict__ qpart,
                          const float* __restrict__ b3,
                          float* __restrict__ qe) {
    int i = blockIdx.x * 256 + threadIdx.x;
    const float4* p = (const float4*)qpart;
    float4 s = p[i];
    float4 s1 = p[16384 + i], s2 = p[32768 + i], s3 = p[49152 + i];
    float4 b = ((const float4*)b3)[i & 511];
    float4 o;
    o.x = fmaxf(s.x + s1.x + s2.x + s3.x + b.x, 0.f);
    o.y = fmaxf(s.y + s1.y + s2.y + s3.y + b.y, 0.f);
    o.z = fmaxf(s.z + s1.z + s2.z + s3.z + b.z, 0.f);
    o.w = fmaxf(s.w + s1.w + s2.w + s3.w + b.w, 0.f);
    ((float4*)qe)[i] = o;
}

// ---- u[n,i,d] = bf16(v[n,i,d] * qe[n,d]) ----
__global__ void make_u(const float* __restrict__ v,
                       const float* __restrict__ qe,
                       uint16_t* __restrict__ u) {
    int idx = blockIdx.x * 256 + threadIdx.x;
    const int total = (N_BATCH * B_OBJ * D_DIM) / 4;
    if (idx >= total) return;
    int d4 = idx % (D_DIM / 4);
    int nb = idx / ((B_OBJ * D_DIM) / 4);
    float4 vv = ((const float4*)v)[idx];
    float4 qq = ((const float4*)qe)[(size_t)nb * (D_DIM / 4) + d4];
    ushort4 o;
    o.x = f2bf(vv.x * qq.x);
    o.y = f2bf(vv.y * qq.y);
    o.z = f2bf(vv.z * qq.z);
    o.w = f2bf(vv.w * qq.w);
    ((ushort4*)u)[idx] = o;
}

// ---- per-batch GEMM: tile M=48(36 real) x N=128, K=2048, BK=64 ----
// Double-buffered LDS pipeline + T2 XOR swizzle.
// LDS rows are 64 B (32 bf16); un-swizzled ds_read_b128 at row stride 64 B puts
// the wave's 64 slots in only 2 of 8 bank-groups (4x conflict). Swizzle: 16B
// slot index ^= (row & 3). global_load_lds writes linearly, so the swizzle is
// applied on the per-lane GLOBAL source address (rule: both sides or neither).
// mode 0: pairsum epilogue -> x (bf16). mode 1: relu(+bias) -> out (f32).
__global__ __launch_bounds__(256) void gemm_batch(
    const uint16_t* __restrict__ A,    // 1152 x 2048 bf16
    const uint16_t* __restrict__ Bt,   // 2048 x 2048 bf16 (n-major)
    const float* __restrict__ bias,
    void* __restrict__ Cv,
    int mode) {
    // Each buffer: As = 48x64 bf16 (3072 u16), Bs = 128x64 bf16 (8192 u16)
    // -> 22528 B per buffer, x2 = 45056 B. Epilogue reuses as yt[48][132] f32.
    __shared__ __align__(16) uint16_t smem[2][11264];
    float* yt = (float*)&smem[0][0];

    int t = threadIdx.x, lane = t & 63, wave = t >> 6;
    int l15 = lane & 15, quad = lane >> 4;
    int nb = blockIdx.y;
    int n0 = blockIdx.x * 128;
    const uint16_t* Ab = A + (size_t)nb * B_OBJ * D_DIM;

    // 22 staging regions of 1KB: 0..5 = A (h=r/3,g=r%3), 6..21 = B (h,g of rb=r-6)
    // Region = 16 rows x 32 u16. Lane -> row (lane>>2), 16B slot (lane&3).
    // Swizzle: lane loads global slot (lane&3)^(row&3) so LDS slot s holds
    // global slot s^(row&3).
    const uint16_t* gp[6];
    int loff[6];
    int wslot = (lane & 3) ^ ((lane >> 2) & 3);
#pragma unroll
    for (int c = 0; c < 6; ++c) {
        int r = wave + 4 * c;
        int rr = (r < 22) ? r : 0;
        if (rr < 6) {
            int h = rr / 3, g = rr % 3;
            int row = g * 16 + (lane >> 2), kk = h * 32 + wslot * 8;
            gp[c] = Ab + (size_t)row * D_DIM + kk;
            loff[c] = h * 1536 + g * 512;
        } else {
            int rb = rr - 6, h = rb >> 3, g = rb & 7;
            int row = g * 16 + (lane >> 2), kk = h * 32 + wslot * 8;
            gp[c] = Bt + (size_t)(n0 + row) * D_DIM + kk;
            loff[c] = 3072 + h * 4096 + g * 512;
        }
    }

    f32x4 acc[3][2] = {};

    // prologue: stage k0=0 into buffer 0
#pragma unroll
    for (int c = 0; c < 6; ++c)
        if (wave + 4 * c < 22) gld_lds16(gp[c], &smem[0][loff[c]]);
    __syncthreads();

    // read-side swizzled slot: all rows this lane reads have row&3 == l15&3
    int rslot = quad ^ (l15 & 3);

    int buf = 0;
    for (int k0 = 0; k0 < D_DIM; k0 += 64) {
        int nk = k0 + 64;
        if (nk < D_DIM) {
            // issue next-tile loads early; they fly while we compute this tile
#pragma unroll
            for (int c = 0; c < 6; ++c)
                if (wave + 4 * c < 22) gld_lds16(gp[c] + nk, &smem[buf ^ 1][loff[c]]);
        }
        const uint16_t* As = &smem[buf][0];
        const uint16_t* Bs = As + 3072;
#pragma unroll
        for (int s = 0; s < 2; ++s) {
            bf16x8 af[3], bfr[2];
#pragma unroll
            for (int i = 0; i < 3; ++i)
                af[i] = *(const bf16x8*)(As + s * 1536 + (i * 16 + l15) * 32 + rslot * 8);
#pragma unroll
            for (int j = 0; j < 2; ++j)
                bfr[j] = *(const bf16x8*)(Bs + s * 4096 + (wave * 32 + j * 16 + l15) * 32 + rslot * 8);
#pragma unroll
            for (int i = 0; i < 3; ++i)
#pragma unroll
                for (int j = 0; j < 2; ++j)
                    acc[i][j] = __builtin_amdgcn_mfma_f32_16x16x32_bf16(af[i], bfr[j], acc[i][j], 0, 0, 0);
        }
        // one barrier per K-step: drains this wave's prefetch (vmcnt) and
        // guarantees all waves finished reading buf before it is overwritten
        __syncthreads();
        buf ^= 1;
    }

    if (mode == 0) {
        uint16_t* X = (uint16_t*)Cv;
        // last __syncthreads already executed at loop end; smem is free
#pragma unroll
        for (int i = 0; i < 3; ++i)
#pragma unroll
            for (int j = 0; j < 2; ++j)
#pragma unroll
                for (int r = 0; r < 4; ++r)
                    yt[(i * 16 + quad * 4 + r) * 132 + wave * 32 + j * 16 + l15] = acc[i][j][r];
        __syncthreads();
        int col = t & 127, half = t >> 7;
        float b = bias[n0 + col];
        float z[36];
#pragma unroll
        for (int j = 0; j < 36; ++j) z[j] = yt[j * 132 + col];
#pragma unroll
        for (int ii = 0; ii < 18; ++ii) {
            int i = half * 18 + ii;
            float zi = z[i] + b;
            float s = 0.f;
#pragma unroll
            for (int j = 0; j < 36; ++j) s += fmaxf(zi + z[j], 0.f);
            X[(size_t)(nb * B_OBJ + i) * D_DIM + n0 + col] = f2bf(s);
        }
    } else {
        float* O = (float*)Cv;
#pragma unroll
        for (int i = 0; i < 3; ++i)
#pragma unroll
            for (int r = 0; r < 4; ++r) {
                int row = i * 16 + quad * 4 + r;
                if (row < B_OBJ) {
#pragma unroll
                    for (int j = 0; j < 2; ++j) {
                        int cc = n0 + wave * 32 + j * 16 + l15;
                        O[(size_t)(nb * B_OBJ + row) * D_DIM + cc] =
                            fmaxf(acc[i][j][r] + bias[cc], 0.f);
                    }
                }
            }
    }
}

extern "C" void kernel_launch(void* const* d_in, const int* in_sizes, int n_in,
                              void* d_out, int out_size, void* d_ws, size_t ws_size,
                              hipStream_t stream) {
    const float* v  = (const float*)d_in[0];
    const float* q  = (const float*)d_in[1];
    const float* W1 = (const float*)d_in[2];
    const float* b1 = (const float*)d_in[3];
    const float* W2 = (const float*)d_in[4];
    const float* b2 = (const float*)d_in[5];
    const float* W3 = (const float*)d_in[6];
    const float* b3 = (const float*)d_in[7];
    float* out = (float*)d_out;

    char* ws = (char*)d_ws;
    uint16_t* W1t   = (uint16_t*)(ws + 0);           // 8 MiB
    uint16_t* W2t   = (uint16_t*)(ws + 8388608);     // 8 MiB
    uint16_t* W3t   = (uint16_t*)(ws + 16777216);    // 4 MiB, dead after qk_gemm
    uint16_t* u     = (uint16_t*)(ws + 16777216);    // 4.5 MiB (overlays dead W3t)
    float*    qpart = (float*)   (ws + 21495808);    // 1 MiB (also pads u over-reads)
    float*    qe    = (float*)   (ws + 22544384);    // 256 KiB
    uint16_t* x     = (uint16_t*)(ws + 22806528);    // 4.5 MiB (ends 27525120)

    transpose_all<<<dim3(32, 80), 256, 0, stream>>>(W1, W2, W3, W1t, W2t, W3t);

    qk_gemm<<<dim3(16, 4), 256, 0, stream>>>(q, W3t, qpart);
    qe_reduce<<<64, 256, 0, stream>>>(qpart, b3, qe);

    make_u<<<(N_BATCH * B_OBJ * D_DIM / 4 + 255) / 256, 256, 0, stream>>>(v, qe, u);

    // GEMM1 + fused pairsum -> x (bf16)
    gemm_batch<<<dim3(16, N_BATCH), 256, 0, stream>>>(u, W1t, b1, x, 0);

    // GEMM2 + bias + relu -> out (f32)
    gemm_batch<<<dim3(16, N_BATCH), 256, 0, stream>>>(x, W2t, b2, out, 1);
}

// Round 3
// 174.488 us; speedup vs baseline: 1.0249x; 1.0249x over previous
//
#include <hip/hip_runtime.h>
#include <stdint.h>

#define N_BATCH 32
#define B_OBJ   36
#define D_DIM   2048
#define Q_DIM   1024

typedef __bf16 bf16x8 __attribute__((ext_vector_type(8)));
typedef float  f32x4  __attribute__((ext_vector_type(4)));

__device__ __forceinline__ uint16_t f2bf(float f) {
    uint32_t u = __builtin_bit_cast(uint32_t, f);
    uint32_t r = (u + 0x7FFFu + ((u >> 16) & 1u)) >> 16;   // RNE
    return (uint16_t)r;
}

__device__ __forceinline__ void gld_lds16(const void* g, void* l) {
    __builtin_amdgcn_global_load_lds(
        (const __attribute__((address_space(1))) uint32_t*)g,
        (__attribute__((address_space(3))) uint32_t*)l, 16, 0, 0);
}

// ---- transpose + fp32->bf16, 64x64 tiles, vectorized ----
__global__ __launch_bounds__(256) void transpose_all(
    const float* __restrict__ W1, const float* __restrict__ W2,
    const float* __restrict__ W3,
    uint16_t* __restrict__ W1t, uint16_t* __restrict__ W2t,
    uint16_t* __restrict__ W3t) {
    __shared__ float tile[64][65];
    int gy = blockIdx.y;
    const float* W; uint16_t* Wt; int K, k0;
    if (gy < 32)      { W = W1; Wt = W1t; K = 2048; k0 = gy * 64; }
    else if (gy < 64) { W = W2; Wt = W2t; K = 2048; k0 = (gy - 32) * 64; }
    else              { W = W3; Wt = W3t; K = 1024; k0 = (gy - 64) * 64; }
    int n0 = blockIdx.x * 64;
    int t = threadIdx.x;
    {
        int r = t >> 4, c = (t & 15) * 4;
#pragma unroll
        for (int p = 0; p < 4; ++p)
            *(float4*)&tile[r + p * 16][c] =
                *(const float4*)&W[(size_t)(k0 + r + p * 16) * 2048 + n0 + c];
    }
    __syncthreads();
    {
        int n = t >> 2, kb = (t & 3) * 16;
#pragma unroll
        for (int g4 = 0; g4 < 4; ++g4) {
            int k = kb + g4 * 4;
            ushort4 o;
            o.x = f2bf(tile[k][n]);     o.y = f2bf(tile[k + 1][n]);
            o.z = f2bf(tile[k + 2][n]); o.w = f2bf(tile[k + 3][n]);
            *(ushort4*)&Wt[(size_t)(n0 + n) * K + k0 + k] = o;
        }
    }
}

// ---- qe GEMM: qpart[z] = q @ W3 over K-chunk z (M=32, N=2048, split-K=4) ----
__global__ __launch_bounds__(256) void qk_gemm(
    const float* __restrict__ q,
    const uint16_t* __restrict__ W3t,
    float* __restrict__ qpart) {
    __shared__ __align__(16) uint16_t As[32][32];
    __shared__ __align__(16) uint16_t Bs[128][32];
    int t = threadIdx.x, lane = t & 63, wave = t >> 6;
    int l15 = lane & 15, quad = lane >> 4;
    int n0 = blockIdx.x * 128;
    int kbase = blockIdx.y * 256;
    f32x4 acc[2][2] = {};
    int ar = t >> 3, ac = (t & 7) * 4;
    int br = t >> 2, bk = (t & 3) * 8;

    for (int k0 = 0; k0 < 256; k0 += 32) {
        __syncthreads();
        float4 av = *(const float4*)&q[(size_t)ar * Q_DIM + kbase + k0 + ac];
        ushort4 a4;
        a4.x = f2bf(av.x); a4.y = f2bf(av.y); a4.z = f2bf(av.z); a4.w = f2bf(av.w);
        *(ushort4*)&As[ar][ac] = a4;
        *(uint4*)&Bs[br][bk]      = *(const uint4*)&W3t[(size_t)(n0 + br) * Q_DIM + kbase + k0 + bk];
        *(uint4*)&Bs[br + 64][bk] = *(const uint4*)&W3t[(size_t)(n0 + br + 64) * Q_DIM + kbase + k0 + bk];
        __syncthreads();
        bf16x8 af[2], bfr[2];
        af[0]  = *(const bf16x8*)&As[l15][quad * 8];
        af[1]  = *(const bf16x8*)&As[16 + l15][quad * 8];
        bfr[0] = *(const bf16x8*)&Bs[wave * 32 + l15][quad * 8];
        bfr[1] = *(const bf16x8*)&Bs[wave * 32 + 16 + l15][quad * 8];
#pragma unroll
        for (int i = 0; i < 2; ++i)
#pragma unroll
            for (int j = 0; j < 2; ++j)
                acc[i][j] = __builtin_amdgcn_mfma_f32_16x16x32_bf16(af[i], bfr[j], acc[i][j], 0, 0, 0);
    }
    float* dst = qpart + (size_t)blockIdx.y * 32 * D_DIM;
#pragma unroll
    for (int i = 0; i < 2; ++i)
#pragma unroll
        for (int j = 0; j < 2; ++j) {
            int n = n0 + wave * 32 + j * 16 + l15;
#pragma unroll
            for (int r = 0; r < 4; ++r)
                dst[(size_t)(i * 16 + quad * 4 + r) * D_DIM + n] = acc[i][j][r];
        }
}

// ---- qe = relu(sum_z qpart + b3) ----
__global__ void qe_reduce(const float* __restrict__ qpart,
                          const float* __restrict__ b3,
                          float* __restrict__ qe) {
    int i = blockIdx.x * 256 + threadIdx.x;
    const float4* p = (const float4*)qpart;
    float4 s = p[i];
    float4 s1 = p[16384 + i], s2 = p[32768 + i], s3 = p[49152 + i];
    float4 b = ((const float4*)b3)[i & 511];
    float4 o;
    o.x = fmaxf(s.x + s1.x + s2.x + s3.x + b.x, 0.f);
    o.y = fmaxf(s.y + s1.y + s2.y + s3.y + b.y, 0.f);
    o.z = fmaxf(s.z + s1.z + s2.z + s3.z + b.z, 0.f);
    o.w = fmaxf(s.w + s1.w + s2.w + s3.w + b.w, 0.f);
    ((float4*)qe)[i] = o;
}

// ---- u[n,i,d] = bf16(v[n,i,d] * qe[n,d]) ----
__global__ void make_u(const float* __restrict__ v,
                       const float* __restrict__ qe,
                       uint16_t* __restrict__ u) {
    int idx = blockIdx.x * 256 + threadIdx.x;
    const int total = (N_BATCH * B_OBJ * D_DIM) / 4;
    if (idx >= total) return;
    int d4 = idx % (D_DIM / 4);
    int nb = idx / ((B_OBJ * D_DIM) / 4);
    float4 vv = ((const float4*)v)[idx];
    float4 qq = ((const float4*)qe)[(size_t)nb * (D_DIM / 4) + d4];
    ushort4 o;
    o.x = f2bf(vv.x * qq.x);
    o.y = f2bf(vv.y * qq.y);
    o.z = f2bf(vv.z * qq.z);
    o.w = f2bf(vv.w * qq.w);
    ((ushort4*)u)[idx] = o;
}

// ---- per-batch GEMM: tile M=48(36 real) x N=128, K=2048, BK=64 ----
// T4 counted-vmcnt pipeline: depth-2 prefetch, raw s_barrier (NO vmcnt(0)
// drain in the loop). Each wave issues exactly 6 global_load_lds per K-step
// (24 regions: A padded to 8, B 16); before computing step k+1 we wait
// s_waitcnt vmcnt(6) -> stage(k+1) retired, stage(k+2)'s 6 loads stay in
// flight across both barriers. A-pad rows 48..63 are staged but never read.
// mode 0: pairsum epilogue -> x (bf16). mode 1: relu(+bias) -> out (f32).
__global__ __launch_bounds__(256) void gemm_batch(
    const uint16_t* __restrict__ A,    // 1152 x 2048 bf16
    const uint16_t* __restrict__ Bt,   // 2048 x 2048 bf16 (n-major)
    const float* __restrict__ bias,
    void* __restrict__ Cv,
    int mode) {
    // Buffer: As = 64x64 bf16 (4096 u16, rows 48-63 junk pad), Bs = 128x64
    // bf16 (8192 u16) -> 24576 B; x2 = 49152 B. Epilogue yt[48][132] f32.
    __shared__ __align__(16) uint16_t smem[2][12288];
    float* yt = (float*)&smem[0][0];

    int t = threadIdx.x, lane = t & 63, wave = t >> 6;
    int l15 = lane & 15, quad = lane >> 4;
    int nb = blockIdx.y;
    int n0 = blockIdx.x * 128;
    const uint16_t* Ab = A + (size_t)nb * B_OBJ * D_DIM;

    // 24 regions of 1KB, r = wave + 4c (6 per wave, uniform):
    //  r 0..7  = A: h=r>>2, g=r&3, rows g*16..g*16+15 (of 64), halves h of K64
    //  r 8..23 = B: rb=r-8: h=rb>>3, g=rb&7, rows g*16.. (of 128)
    // Region = 16 rows x 32 u16; lane -> row lane>>2, swizzled 16B slot.
    const uint16_t* gp[6];
    int loff[6];
    int wslot = (lane & 3) ^ ((lane >> 2) & 3);
#pragma unroll
    for (int c = 0; c < 6; ++c) {
        int r = wave + 4 * c;
        if (r < 8) {
            int h = r >> 2, g = r & 3;
            int row = g * 16 + (lane >> 2), kk = h * 32 + wslot * 8;
            gp[c] = Ab + (size_t)row * D_DIM + kk;   // rows >= 48: junk, never read
            loff[c] = h * 2048 + g * 512;
        } else {
            int rb = r - 8, h = rb >> 3, g = rb & 7;
            int row = g * 16 + (lane >> 2), kk = h * 32 + wslot * 8;
            gp[c] = Bt + (size_t)(n0 + row) * D_DIM + kk;
            loff[c] = 4096 + h * 4096 + g * 512;
        }
    }

    f32x4 acc[3][2] = {};
    // read-side swizzled slot: all rows this lane reads have row&3 == l15&3
    int rslot = quad ^ (l15 & 3);

#define STAGE(kk, bi)                                   \
    {                                                   \
        _Pragma("unroll")                               \
        for (int c = 0; c < 6; ++c)                     \
            gld_lds16(gp[c] + (kk), &smem[bi][loff[c]]); \
    }

    // prologue: fill both buffers, wait only for buf0's 6 (stage-1 stays in flight)
    STAGE(0, 0);
    STAGE(64, 1);
    asm volatile("s_waitcnt vmcnt(6)" ::: "memory");
    __builtin_amdgcn_s_barrier();

    int cur = 0;
    for (int k = 0; k < 32; ++k) {
        const uint16_t* As = &smem[cur][0];
        const uint16_t* Bs = As + 4096;
#pragma unroll
        for (int s = 0; s < 2; ++s) {
            bf16x8 af[3], bfr[2];
#pragma unroll
            for (int i = 0; i < 3; ++i)
                af[i] = *(const bf16x8*)(As + s * 2048 + (i * 16 + l15) * 32 + rslot * 8);
#pragma unroll
            for (int j = 0; j < 2; ++j)
                bfr[j] = *(const bf16x8*)(Bs + s * 4096 + (wave * 32 + j * 16 + l15) * 32 + rslot * 8);
#pragma unroll
            for (int i = 0; i < 3; ++i)
#pragma unroll
                for (int j = 0; j < 2; ++j)
                    acc[i][j] = __builtin_amdgcn_mfma_f32_16x16x32_bf16(af[i], bfr[j], acc[i][j], 0, 0, 0);
        }
        if (k == 31) break;
        __builtin_amdgcn_s_barrier();          // all waves done reading buf[cur]
        if (k + 2 < 32) {
            STAGE((k + 2) * 64, cur);          // refill freed buffer; 6 loads
            asm volatile("s_waitcnt vmcnt(6)" ::: "memory");  // stage(k+1) retired
        } else {
            asm volatile("s_waitcnt vmcnt(0)" ::: "memory");  // tail: drain stage(31)
        }
        __builtin_amdgcn_s_barrier();          // buf[cur^1] ready for step k+1
        cur ^= 1;
    }
#undef STAGE

    if (mode == 0) {
        uint16_t* X = (uint16_t*)Cv;
        __syncthreads();   // all waves done with K-loop before smem reuse as yt
#pragma unroll
        for (int i = 0; i < 3; ++i)
#pragma unroll
            for (int j = 0; j < 2; ++j)
#pragma unroll
                for (int r = 0; r < 4; ++r)
                    yt[(i * 16 + quad * 4 + r) * 132 + wave * 32 + j * 16 + l15] = acc[i][j][r];
        __syncthreads();
        int col = t & 127, half = t >> 7;
        float b = bias[n0 + col];
        float z[36];
#pragma unroll
        for (int j = 0; j < 36; ++j) z[j] = yt[j * 132 + col];
#pragma unroll
        for (int ii = 0; ii < 18; ++ii) {
            int i = half * 18 + ii;
            float zi = z[i] + b;
            float s = 0.f;
#pragma unroll
            for (int j = 0; j < 36; ++j) s += fmaxf(zi + z[j], 0.f);
            X[(size_t)(nb * B_OBJ + i) * D_DIM + n0 + col] = f2bf(s);
        }
    } else {
        float* O = (float*)Cv;
#pragma unroll
        for (int i = 0; i < 3; ++i)
#pragma unroll
            for (int r = 0; r < 4; ++r) {
                int row = i * 16 + quad * 4 + r;
                if (row < B_OBJ) {
#pragma unroll
                    for (int j = 0; j < 2; ++j) {
                        int cc = n0 + wave * 32 + j * 16 + l15;
                        O[(size_t)(nb * B_OBJ + row) * D_DIM + cc] =
                            fmaxf(acc[i][j][r] + bias[cc], 0.f);
                    }
                }
            }
    }
}

extern "C" void kernel_launch(void* const* d_in, const int* in_sizes, int n_in,
                              void* d_out, int out_size, void* d_ws, size_t ws_size,
                              hipStream_t stream) {
    const float* v  = (const float*)d_in[0];
    const float* q  = (const float*)d_in[1];
    const float* W1 = (const float*)d_in[2];
    const float* b1 = (const float*)d_in[3];
    const float* W2 = (const float*)d_in[4];
    const float* b2 = (const float*)d_in[5];
    const float* W3 = (const float*)d_in[6];
    const float* b3 = (const float*)d_in[7];
    float* out = (float*)d_out;

    char* ws = (char*)d_ws;
    uint16_t* W1t   = (uint16_t*)(ws + 0);           // 8 MiB
    uint16_t* W2t   = (uint16_t*)(ws + 8388608);     // 8 MiB
    uint16_t* W3t   = (uint16_t*)(ws + 16777216);    // 4 MiB, dead after qk_gemm
    uint16_t* u     = (uint16_t*)(ws + 16777216);    // 4.5 MiB (overlays dead W3t)
    float*    qpart = (float*)   (ws + 21495808);    // 1 MiB (also pads u over-reads)
    float*    qe    = (float*)   (ws + 22544384);    // 256 KiB
    uint16_t* x     = (uint16_t*)(ws + 22806528);    // 4.5 MiB (ends 27525120)

    transpose_all<<<dim3(32, 80), 256, 0, stream>>>(W1, W2, W3, W1t, W2t, W3t);

    qk_gemm<<<dim3(16, 4), 256, 0, stream>>>(q, W3t, qpart);
    qe_reduce<<<64, 256, 0, stream>>>(qpart, b3, qe);

    make_u<<<(N_BATCH * B_OBJ * D_DIM / 4 + 255) / 256, 256, 0, stream>>>(v, qe, u);

    // GEMM1 + fused pairsum -> x (bf16)
    gemm_batch<<<dim3(16, N_BATCH), 256, 0, stream>>>(u, W1t, b1, x, 0);

    // GEMM2 + bias + relu -> out (f32)
    gemm_batch<<<dim3(16, N_BATCH), 256, 0, stream>>>(x, W2t, b2, out, 1);
}